// Round 6
// baseline (162.564 us; speedup 1.0000x reference)
//
#include <hip/hip_runtime.h>
#include <stdint.h>

// ---------------------------------------------------------------------------
// VQ-VAE VectorQuantizer forward (MI355X):
//   out  = encoderout (faithful source bug)
//   loss_sum = sum_all x^2 + sum_m min_n (||e_n||^2 - 2 x_m.e_n)
//   cbl = loss_sum/ELEMS ; comm = cbl ; loss = 1.25*cbl
// enc [32,256,32,32] f32 NCHW, codebook [1024,256] f32.
// R7 = R6 resubmit minus the redundant amdgpu_waves_per_eu attribute
// (stacked with __launch_bounds__(256,2) it was the only non-standard
// construct in the container-failed run; launch_bounds alone already pins
// 2 waves/SIMD). R6 rationale: R5 Occupancy ~15% = 1 wave/SIMD -> every
// wait a dead stall; cut phase-A reg peak (vh[8] batches, same FP order),
// depth-2 B prefetch (bfa/bfb) to cover L2 latency at 2 waves/SIMD.
// ---------------------------------------------------------------------------

#define EMB 256
#define ELEMS 8388608   // 32*256*32*32
#define NBLK 512

typedef __bf16 bf16x8 __attribute__((ext_vector_type(8)));
typedef float  f32x4  __attribute__((ext_vector_type(4)));

union Frag { uint4 u4; bf16x8 v; };

__device__ __forceinline__ unsigned short f2bf(float f) {
    unsigned u = __float_as_uint(f);
    u += 0x7FFFu + ((u >> 16) & 1u);   // RNE
    return (unsigned short)(u >> 16);
}

// ---------------------------------------------------------------------------
// prep: codebook f32 [1024][256] -> bf16 fragment-ordered global layout:
//   uint4 granule index = nc*2048 + ks*256 + (n&63)*4 + q
//   (nc = n>>6 chunk of 64 codes; ks = K-step 0..7; q = 8-elem K-quad)
// esq[n] = ||e_n||^2. Also zeroes accum + done.
// ---------------------------------------------------------------------------
__global__ __launch_bounds__(256) void vq_prep(const float* __restrict__ cb,
                                               uint2* __restrict__ cbswz,
                                               float* __restrict__ esq,
                                               float* __restrict__ accum,
                                               unsigned* __restrict__ done) {
    if (blockIdx.x == 0 && threadIdx.x == 0) { accum[0] = 0.f; done[0] = 0u; }

    const int tid  = threadIdx.x;
    const int w    = tid >> 6;
    const int lane = tid & 63;
    const int n    = blockIdx.x * 4 + w;

    const float4* row = (const float4*)(cb + n * EMB);
    float4 v = row[lane];                       // k = 4*lane .. 4*lane+3

    float s = v.x * v.x + v.y * v.y + v.z * v.z + v.w * v.w;
    #pragma unroll
    for (int m = 1; m <= 32; m <<= 1) s += __shfl_xor(s, m);
    if (lane == 0) esq[n] = s;

    unsigned lo = (unsigned)f2bf(v.x) | ((unsigned)f2bf(v.y) << 16);
    unsigned hi = (unsigned)f2bf(v.z) | ((unsigned)f2bf(v.w) << 16);
    const int kc = lane >> 1;          // 16B K-granule 0..31 (8 bf16)
    const int h  = lane & 1;           // low/high uint2 of the granule
    const unsigned idx4 = ((unsigned)(n >> 6) << 11) + ((unsigned)(kc >> 2) << 8)
                        + ((unsigned)(n & 63) << 2) + (unsigned)(kc & 3);
    cbswz[idx4 * 2 + h] = make_uint2(lo, hi);
}

// ---------------------------------------------------------------------------
// main: block = 64 hw-rows of one image; 4 waves; grid 512 (2 blocks/CU).
// Each wave: all 64 rows (mi=0..3), codes w*16..w*16+15 of each 64-chunk.
// ---------------------------------------------------------------------------

#define CHUNK_R6(nc_, BUF_, PF_, pfc_) do {                                    \
    f32x4 _a0 = (f32x4){0.f,0.f,0.f,0.f};                                      \
    f32x4 _a1 = (f32x4){0.f,0.f,0.f,0.f};                                      \
    f32x4 _a2 = (f32x4){0.f,0.f,0.f,0.f};                                      \
    f32x4 _a3 = (f32x4){0.f,0.f,0.f,0.f};                                      \
    _Pragma("unroll")                                                          \
    for (int _ks = 0; _ks < 8; ++_ks) {                                        \
        bf16x8 _bv = BUF_[_ks].v;                                              \
        _a0 = __builtin_amdgcn_mfma_f32_16x16x32_bf16(afr[0][_ks], _bv, _a0, 0, 0, 0); \
        _a1 = __builtin_amdgcn_mfma_f32_16x16x32_bf16(afr[1][_ks], _bv, _a1, 0, 0, 0); \
        _a2 = __builtin_amdgcn_mfma_f32_16x16x32_bf16(afr[2][_ks], _bv, _a2, 0, 0, 0); \
        _a3 = __builtin_amdgcn_mfma_f32_16x16x32_bf16(afr[3][_ks], _bv, _a3, 0, 0, 0); \
        if (PF_)   /* depth-2 rolling prefetch into same frag slot */          \
            BUF_[_ks].u4 = pc[(size_t)(pfc_) * 2048 + _ks * 256];              \
    }                                                                          \
    const float _eq = esq[(nc_) * 64 + nl];                                    \
    _Pragma("unroll")                                                          \
    for (int _r2 = 0; _r2 < 4; ++_r2) {                                        \
        rmin[0][_r2] = fminf(rmin[0][_r2], fmaf(-2.f, _a0[_r2], _eq));         \
        rmin[1][_r2] = fminf(rmin[1][_r2], fmaf(-2.f, _a1[_r2], _eq));         \
        rmin[2][_r2] = fminf(rmin[2][_r2], fmaf(-2.f, _a2[_r2], _eq));         \
        rmin[3][_r2] = fminf(rmin[3][_r2], fmaf(-2.f, _a3[_r2], _eq));         \
    } } while (0)

__global__ __launch_bounds__(256, 2)
void vq_main(const float* __restrict__ enc,
             const uint4* __restrict__ cbswz,
             const float* __restrict__ esq,
             float* __restrict__ out,
             float* __restrict__ accum,
             unsigned* __restrict__ done) {
    __shared__ uint4 As[2048];          // 32 KB: 64 rows x 512B swizzled (A transpose only)
    __shared__ float dmin[4][64];
    __shared__ float partsA[4];

    const int tid  = threadIdx.x;
    const int w    = tid >> 6;          // wave 0..3 = code subgroup
    const int lane = tid & 63;
    const int q    = lane >> 4;         // quad 0..3
    const int c    = lane & 15;

    const int b   = blockIdx.x >> 4;            // image
    const int hw0 = (blockIdx.x & 15) << 6;     // 64-row slab
    const float* encB = enc + (size_t)b * 262144 + hw0;
    float*       outB = out + (size_t)b * 262144 + hw0;

    const int nl = w * 16 + c;          // this lane's code within each 64-chunk
    const uint4* pc = cbswz + (size_t)(nl * 4 + q);   // per-lane frag base

    // ---- phase A: two 8-load batches (keeps reg peak low). Batch h covers
    //      channels kg*16+h*8 .. +7 = exactly swizzled chunk 2kg+h of each
    //      row. Copy enc->out nontemporal, sum(x^2), bf16 transpose to As.
    const int q4 = tid & 15;            // hw quad (4 hw rows)
    const int kg = tid >> 4;            // 0..15 -> ch0 = kg*16
    float sx = 0.f;
    #pragma unroll
    for (int h2 = 0; h2 < 2; ++h2) {
        f32x4 vh[8];
        #pragma unroll
        for (int j = 0; j < 8; ++j)
            vh[j] = __builtin_nontemporal_load(
                (const f32x4*)(encB + (size_t)(kg * 16 + h2 * 8 + j) * 1024 + q4 * 4));
        #pragma unroll
        for (int j = 0; j < 8; ++j) {
            __builtin_nontemporal_store(vh[j],
                (f32x4*)(outB + (size_t)(kg * 16 + h2 * 8 + j) * 1024 + q4 * 4));
            #pragma unroll
            for (int i2 = 0; i2 < 4; ++i2) sx = fmaf(vh[j][i2], vh[j][i2], sx);
        }
        #pragma unroll
        for (int i = 0; i < 4; ++i) {   // row r = q4*4+i; chunk 2kg+h2
            unsigned short us[8];
            #pragma unroll
            for (int j = 0; j < 8; ++j) us[j] = f2bf(vh[j][i]);
            uint4 pk;
            pk.x = (unsigned)us[0] | ((unsigned)us[1] << 16);
            pk.y = (unsigned)us[2] | ((unsigned)us[3] << 16);
            pk.z = (unsigned)us[4] | ((unsigned)us[5] << 16);
            pk.w = (unsigned)us[6] | ((unsigned)us[7] << 16);
            const int r = q4 * 4 + i;
            As[r * 32 + ((2 * kg + h2) ^ (r & 7))] = pk;
        }
    }

    // ---- B prologue: chunks 0 and 1 into regs; the phase-A barrier's
    //      vmcnt(0) drain doubles as their completion wait.
    Frag bfa[8], bfb[8];
    #pragma unroll
    for (int ks = 0; ks < 8; ++ks) bfa[ks].u4 = pc[ks * 256];
    #pragma unroll
    for (int ks = 0; ks < 8; ++ks) bfb[ks].u4 = pc[2048 + ks * 256];

    #pragma unroll
    for (int m = 1; m <= 32; m <<= 1) sx += __shfl_xor(sx, m);
    if (lane == 0) partsA[w] = sx;
    __syncthreads();                    // As ready + chunk-0/1 B loaded

    // ---- A fragments: 64 rows x full K into registers (mi=4) ----
    bf16x8 afr[4][8];
    #pragma unroll
    for (int mi = 0; mi < 4; ++mi) {
        const int r = mi * 16 + c;
        #pragma unroll
        for (int ks = 0; ks < 8; ++ks) {
            Frag fa; fa.u4 = As[r * 32 + ((ks * 4 + q) ^ (r & 7))];
            afr[mi][ks] = fa.v;
        }
    }

    float rmin[4][4];
    #pragma unroll
    for (int mi = 0; mi < 4; ++mi)
        #pragma unroll
        for (int r2 = 0; r2 < 4; ++r2) rmin[mi][r2] = 1e30f;

    // ---- K-loop: 16 chunks of 64 codes, paired; NO barriers, NO LDS;
    //      depth-2 global->reg prefetch (bfa even chunks, bfb odd). ----
    for (int i = 0; i < 8; ++i) {
        const bool pf = (i < 7);        // wave-uniform
        CHUNK_R6(2 * i,     bfa, pf, 2 * i + 2);
        CHUNK_R6(2 * i + 1, bfb, pf, 2 * i + 3);
    }

    // min across the 16 code-columns (xor over c bits), then per-row mins
    #pragma unroll
    for (int mi = 0; mi < 4; ++mi)
        #pragma unroll
        for (int r2 = 0; r2 < 4; ++r2) {
            float x = rmin[mi][r2];
            x = fminf(x, __shfl_xor(x, 1));
            x = fminf(x, __shfl_xor(x, 2));
            x = fminf(x, __shfl_xor(x, 4));
            x = fminf(x, __shfl_xor(x, 8));
            rmin[mi][r2] = x;
        }
    if (c == 0) {
        #pragma unroll
        for (int mi = 0; mi < 4; ++mi)
            #pragma unroll
            for (int r2 = 0; r2 < 4; ++r2)
                dmin[w][mi * 16 + q * 4 + r2] = rmin[mi][r2];
    }
    __syncthreads();

    if (tid < 64) {
        float vr = fminf(fminf(dmin[0][tid], dmin[1][tid]),
                         fminf(dmin[2][tid], dmin[3][tid]));
        #pragma unroll
        for (int m = 1; m <= 32; m <<= 1) vr += __shfl_xor(vr, m);
        if (tid == 0) {
            float s = vr + partsA[0] + partsA[1] + partsA[2] + partsA[3];
            atomicAdd(accum, s);
            __threadfence();                          // release our add
            unsigned prev = atomicAdd(done, 1u);      // device-scope ticket
            if (prev == NBLK - 1) {
                float tot = atomicAdd(accum, 0.0f);   // coherent read of total
                float cbl = tot * (1.0f / (float)ELEMS);
                out[ELEMS + 0] = 1.25f * cbl;   // loss = cbl + BETA*cbl
                out[ELEMS + 1] = cbl;           // codebook_loss
                out[ELEMS + 2] = cbl;           // commitment_loss
            }
        }
    }
}

extern "C" void kernel_launch(void* const* d_in, const int* in_sizes, int n_in,
                              void* d_out, int out_size, void* d_ws, size_t ws_size,
                              hipStream_t stream) {
    const float* enc = (const float*)d_in[0];
    const float* cb  = (const float*)d_in[1];
    float* out = (float*)d_out;

    float*    accum = (float*)d_ws;                    // 4 B
    unsigned* done  = (unsigned*)((char*)d_ws + 64);   // 4 B
    float*    esq   = (float*)((char*)d_ws + 256);     // 4 KB
    uint2*    cbswz = (uint2*)((char*)d_ws + 8192);    // 512 KB

    vq_prep<<<dim3(256), dim3(256), 0, stream>>>(cb, cbswz, esq, accum, done);
    vq_main<<<dim3(NBLK), dim3(256), 0, stream>>>(enc, (const uint4*)cbswz, esq,
                                                  out, accum, done);
}

// Round 7
// 111.155 us; speedup vs baseline: 1.4625x; 1.4625x over previous
//
#include <hip/hip_runtime.h>
#include <stdint.h>

// ---------------------------------------------------------------------------
// VQ-VAE VectorQuantizer forward (MI355X):
//   out  = encoderout (faithful source bug)
//   loss_sum = sum_all x^2 + sum_m min_n (||e_n||^2 - 2 x_m.e_n)
//   cbl = loss_sum/ELEMS ; comm = cbl ; loss = 1.25*cbl
// enc [32,256,32,32] f32 NCHW, codebook [1024,256] f32.
// R8 = R5 (best main, 42us, VGPR 108, no spills) minus ALL nontemporal
// hints. R6/R7 post-mortem: depth-2 prefetch spilled (VGPR 128, WRITE
// 121MB incl. scratch) -> reverted. NT theory: enc is L3-resident across
// harness iterations and out-stores absorb into L3; NT bypassed both and
// forced HBM traffic inside the timed window (totals regressed 109->116
// while main improved). Plain loads/stores restore L3 service.
// ---------------------------------------------------------------------------

#define EMB 256
#define ELEMS 8388608   // 32*256*32*32
#define NBLK 512

typedef __bf16 bf16x8 __attribute__((ext_vector_type(8)));
typedef float  f32x4  __attribute__((ext_vector_type(4)));

union Frag { uint4 u4; bf16x8 v; };

__device__ __forceinline__ unsigned short f2bf(float f) {
    unsigned u = __float_as_uint(f);
    u += 0x7FFFu + ((u >> 16) & 1u);   // RNE
    return (unsigned short)(u >> 16);
}

// ---------------------------------------------------------------------------
// prep: codebook f32 [1024][256] -> bf16 fragment-ordered global layout:
//   uint4 granule index = nc*2048 + ks*256 + (n&63)*4 + q
//   (nc = n>>6 chunk of 64 codes; ks = K-step 0..7; q = 8-elem K-quad)
// esq[n] = ||e_n||^2. Also zeroes accum + done.
// ---------------------------------------------------------------------------
__global__ __launch_bounds__(256) void vq_prep(const float* __restrict__ cb,
                                               uint2* __restrict__ cbswz,
                                               float* __restrict__ esq,
                                               float* __restrict__ accum,
                                               unsigned* __restrict__ done) {
    if (blockIdx.x == 0 && threadIdx.x == 0) { accum[0] = 0.f; done[0] = 0u; }

    const int tid  = threadIdx.x;
    const int w    = tid >> 6;
    const int lane = tid & 63;
    const int n    = blockIdx.x * 4 + w;

    const float4* row = (const float4*)(cb + n * EMB);
    float4 v = row[lane];                       // k = 4*lane .. 4*lane+3

    float s = v.x * v.x + v.y * v.y + v.z * v.z + v.w * v.w;
    #pragma unroll
    for (int m = 1; m <= 32; m <<= 1) s += __shfl_xor(s, m);
    if (lane == 0) esq[n] = s;

    unsigned lo = (unsigned)f2bf(v.x) | ((unsigned)f2bf(v.y) << 16);
    unsigned hi = (unsigned)f2bf(v.z) | ((unsigned)f2bf(v.w) << 16);
    const int kc = lane >> 1;          // 16B K-granule 0..31 (8 bf16)
    const int h  = lane & 1;           // low/high uint2 of the granule
    const unsigned idx4 = ((unsigned)(n >> 6) << 11) + ((unsigned)(kc >> 2) << 8)
                        + ((unsigned)(n & 63) << 2) + (unsigned)(kc & 3);
    cbswz[idx4 * 2 + h] = make_uint2(lo, hi);
}

// ---------------------------------------------------------------------------
// main: block = 64 hw-rows of one image; 4 waves; grid 512 (2 blocks/CU).
// Each wave: all 64 rows (mi=0..3), codes w*16..w*16+15 of each 64-chunk.
// ---------------------------------------------------------------------------

#define CHUNK_BODY(nc_, LOADNEXT_) do {                                        \
    f32x4 _a0 = (f32x4){0.f,0.f,0.f,0.f};                                      \
    f32x4 _a1 = (f32x4){0.f,0.f,0.f,0.f};                                      \
    f32x4 _a2 = (f32x4){0.f,0.f,0.f,0.f};                                      \
    f32x4 _a3 = (f32x4){0.f,0.f,0.f,0.f};                                      \
    _Pragma("unroll")                                                          \
    for (int _ks = 0; _ks < 8; ++_ks) {                                        \
        bf16x8 _bv = bfr[_ks].v;                                               \
        _a0 = __builtin_amdgcn_mfma_f32_16x16x32_bf16(afr[0][_ks], _bv, _a0, 0, 0, 0); \
        _a1 = __builtin_amdgcn_mfma_f32_16x16x32_bf16(afr[1][_ks], _bv, _a1, 0, 0, 0); \
        _a2 = __builtin_amdgcn_mfma_f32_16x16x32_bf16(afr[2][_ks], _bv, _a2, 0, 0, 0); \
        _a3 = __builtin_amdgcn_mfma_f32_16x16x32_bf16(afr[3][_ks], _bv, _a3, 0, 0, 0); \
        if (LOADNEXT_)   /* rolling prefetch: chunk nc+1, same frag slot */    \
            bfr[_ks].u4 = pc[((nc_) + 1) * 2048 + _ks * 256];                  \
    }                                                                          \
    const float _eq = esq[(nc_) * 64 + nl];                                    \
    _Pragma("unroll")                                                          \
    for (int _r2 = 0; _r2 < 4; ++_r2) {                                        \
        rmin[0][_r2] = fminf(rmin[0][_r2], fmaf(-2.f, _a0[_r2], _eq));         \
        rmin[1][_r2] = fminf(rmin[1][_r2], fmaf(-2.f, _a1[_r2], _eq));         \
        rmin[2][_r2] = fminf(rmin[2][_r2], fmaf(-2.f, _a2[_r2], _eq));         \
        rmin[3][_r2] = fminf(rmin[3][_r2], fmaf(-2.f, _a3[_r2], _eq));         \
    } } while (0)

__global__ __launch_bounds__(256, 2)
void vq_main(const float* __restrict__ enc,
             const uint4* __restrict__ cbswz,
             const float* __restrict__ esq,
             float* __restrict__ out,
             float* __restrict__ accum,
             unsigned* __restrict__ done) {
    __shared__ uint4 As[2048];          // 32 KB: 64 rows x 512B swizzled (A transpose only)
    __shared__ float dmin[4][64];
    __shared__ float partsA[4];

    const int tid  = threadIdx.x;
    const int w    = tid >> 6;          // wave 0..3 = code subgroup
    const int lane = tid & 63;
    const int q    = lane >> 4;         // quad 0..3
    const int c    = lane & 15;

    const int b   = blockIdx.x >> 4;            // image
    const int hw0 = (blockIdx.x & 15) << 6;     // 64-row slab
    const float* encB = enc + (size_t)b * 262144 + hw0;
    float*       outB = out + (size_t)b * 262144 + hw0;

    const int nl = w * 16 + c;          // this lane's code within each 64-chunk
    const uint4* pc = cbswz + (size_t)(nl * 4 + q);   // per-lane frag base

    // ---- phase A: copy enc->out (plain loads/stores; enc is L3-resident
    //      across iterations, out absorbs into L3), sum(x^2), bf16
    //      transpose into swizzled As. 16 float4 per thread = 64 rows x 256ch.
    const int q4 = tid & 15;            // hw quad (4 hw rows)
    const int kg = tid >> 4;            // 0..15 -> ch0 = kg*16
    float sx = 0.f;
    {
        f32x4 vh[16];
        #pragma unroll
        for (int j = 0; j < 16; ++j)
            vh[j] = *(const f32x4*)(encB + (size_t)(kg * 16 + j) * 1024 + q4 * 4);
        #pragma unroll
        for (int j = 0; j < 16; ++j) {
            *(f32x4*)(outB + (size_t)(kg * 16 + j) * 1024 + q4 * 4) = vh[j];
            #pragma unroll
            for (int i2 = 0; i2 < 4; ++i2) sx = fmaf(vh[j][i2], vh[j][i2], sx);
        }
        #pragma unroll
        for (int i = 0; i < 4; ++i) {   // row r = q4*4+i; chunks 2kg, 2kg+1
            unsigned short us[16];
            #pragma unroll
            for (int j = 0; j < 16; ++j) us[j] = f2bf(vh[j][i]);
            uint4 pk0, pk1;
            pk0.x = (unsigned)us[0]  | ((unsigned)us[1]  << 16);
            pk0.y = (unsigned)us[2]  | ((unsigned)us[3]  << 16);
            pk0.z = (unsigned)us[4]  | ((unsigned)us[5]  << 16);
            pk0.w = (unsigned)us[6]  | ((unsigned)us[7]  << 16);
            pk1.x = (unsigned)us[8]  | ((unsigned)us[9]  << 16);
            pk1.y = (unsigned)us[10] | ((unsigned)us[11] << 16);
            pk1.z = (unsigned)us[12] | ((unsigned)us[13] << 16);
            pk1.w = (unsigned)us[14] | ((unsigned)us[15] << 16);
            const int r = q4 * 4 + i;
            As[r * 32 + ((2 * kg + 0) ^ (r & 7))] = pk0;
            As[r * 32 + ((2 * kg + 1) ^ (r & 7))] = pk1;
        }
    }

    // ---- chunk-0 B prologue: issue now; the phase-A barrier's vmcnt(0)
    //      drain doubles as their completion wait (zero extra stall).
    Frag bfr[8];
    #pragma unroll
    for (int ks = 0; ks < 8; ++ks) bfr[ks].u4 = pc[ks * 256];

    #pragma unroll
    for (int m = 1; m <= 32; m <<= 1) sx += __shfl_xor(sx, m);
    if (lane == 0) partsA[w] = sx;
    __syncthreads();                    // As ready + chunk-0 B loaded

    // ---- A fragments: 64 rows x full K into registers (mi=4) ----
    bf16x8 afr[4][8];
    #pragma unroll
    for (int mi = 0; mi < 4; ++mi) {
        const int r = mi * 16 + c;
        #pragma unroll
        for (int ks = 0; ks < 8; ++ks) {
            Frag fa; fa.u4 = As[r * 32 + ((ks * 4 + q) ^ (r & 7))];
            afr[mi][ks] = fa.v;
        }
    }

    float rmin[4][4];
    #pragma unroll
    for (int mi = 0; mi < 4; ++mi)
        #pragma unroll
        for (int r2 = 0; r2 < 4; ++r2) rmin[mi][r2] = 1e30f;

    // ---- K-loop: 16 chunks of 64 codes; NO barriers, NO LDS; rolling
    //      global->reg prefetch one chunk ahead. ----
    for (int nc = 0; nc < 15; ++nc) CHUNK_BODY(nc, 1);
    CHUNK_BODY(15, 0);

    // min across the 16 code-columns (xor over c bits), then per-row mins
    #pragma unroll
    for (int mi = 0; mi < 4; ++mi)
        #pragma unroll
        for (int r2 = 0; r2 < 4; ++r2) {
            float x = rmin[mi][r2];
            x = fminf(x, __shfl_xor(x, 1));
            x = fminf(x, __shfl_xor(x, 2));
            x = fminf(x, __shfl_xor(x, 4));
            x = fminf(x, __shfl_xor(x, 8));
            rmin[mi][r2] = x;
        }
    if (c == 0) {
        #pragma unroll
        for (int mi = 0; mi < 4; ++mi)
            #pragma unroll
            for (int r2 = 0; r2 < 4; ++r2)
                dmin[w][mi * 16 + q * 4 + r2] = rmin[mi][r2];
    }
    __syncthreads();

    if (tid < 64) {
        float vr = fminf(fminf(dmin[0][tid], dmin[1][tid]),
                         fminf(dmin[2][tid], dmin[3][tid]));
        #pragma unroll
        for (int m = 1; m <= 32; m <<= 1) vr += __shfl_xor(vr, m);
        if (tid == 0) {
            float s = vr + partsA[0] + partsA[1] + partsA[2] + partsA[3];
            atomicAdd(accum, s);
            __threadfence();                          // release our add
            unsigned prev = atomicAdd(done, 1u);      // device-scope ticket
            if (prev == NBLK - 1) {
                float tot = atomicAdd(accum, 0.0f);   // coherent read of total
                float cbl = tot * (1.0f / (float)ELEMS);
                out[ELEMS + 0] = 1.25f * cbl;   // loss = cbl + BETA*cbl
                out[ELEMS + 1] = cbl;           // codebook_loss
                out[ELEMS + 2] = cbl;           // commitment_loss
            }
        }
    }
}

extern "C" void kernel_launch(void* const* d_in, const int* in_sizes, int n_in,
                              void* d_out, int out_size, void* d_ws, size_t ws_size,
                              hipStream_t stream) {
    const float* enc = (const float*)d_in[0];
    const float* cb  = (const float*)d_in[1];
    float* out = (float*)d_out;

    float*    accum = (float*)d_ws;                    // 4 B
    unsigned* done  = (unsigned*)((char*)d_ws + 64);   // 4 B
    float*    esq   = (float*)((char*)d_ws + 256);     // 4 KB
    uint2*    cbswz = (uint2*)((char*)d_ws + 8192);    // 512 KB

    vq_prep<<<dim3(256), dim3(256), 0, stream>>>(cb, cbswz, esq, accum, done);
    vq_main<<<dim3(NBLK), dim3(256), 0, stream>>>(enc, (const uint4*)cbswz, esq,
                                                  out, accum, done);
}